// Round 1
// baseline (618.340 us; speedup 1.0000x reference)
//
#include <hip/hip_runtime.h>
#include <hip/hip_bf16.h>

// Hopfield forward, factored Gauss-Seidel (no W materialization).
// p~_l = sum_j x[l,j] s_j  (512-dim state, 8 per lane in one wave)
// v_i*512 = S~_i - rho*P~ - A_i*T - f_i ;  S~_i = sum_l x[l,i] p~_l
//   A_i = rho*c_i - 512*rho^2, f_i = q_i*s0_i, q_i = 512(1+rho^2)-2*rho*c_i
// update: d = sign(v) - s0_i ; p~_l += x[l,i]*d ; P~ += d*c_i ; T += d

#define WS_SGN_OFF   0u                 // float[4096][512] sign(+-1.0f) of llv^T : 8 MB
#define WS_CST_OFF   (8u<<20)           // float4[4096] {f, A, dp, c} : 64 KB
#define WS_XBITS_OFF (WS_CST_OFF + 4096u*16u)      // u64[512*64] packed x rows : 256 KB
#define WS_P0_OFF    (WS_XBITS_OFF + 512u*64u*8u)  // float[512] p~ init
#define WS_SBITS_OFF (WS_P0_OFF + 2048u)           // u64[64] packed final s
#define WS_CNT_OFF   (WS_SBITS_OFF + 512u)         // int[4096] column positive counts
#define WS_HDR_OFF   (WS_CNT_OFF + 16384u)         // float[16] header (rho)

template<int CTRL, int RMASK>
__device__ __forceinline__ float dpp_add(float x){
  int t = __builtin_amdgcn_update_dpp(0, __float_as_int(x), CTRL, RMASK, 0xf, true);
  return x + __int_as_float(t);
}
// full 64-lane sum, result broadcast to all lanes via readlane (VALU/DPP only, no LDS)
__device__ __forceinline__ float wave_allsum(float x){
  x = dpp_add<0x111,0xf>(x);  // row_shr:1
  x = dpp_add<0x112,0xf>(x);  // row_shr:2
  x = dpp_add<0x114,0xf>(x);  // row_shr:4
  x = dpp_add<0x118,0xf>(x);  // row_shr:8
  x = dpp_add<0x142,0xa>(x);  // row_bcast:15 -> rows 1,3
  x = dpp_add<0x143,0xc>(x);  // row_bcast:31 -> rows 2,3 ; lane63 = total
  return __int_as_float(__builtin_amdgcn_readlane(__float_as_int(x), 63));
}

// ---- k1: sign-transpose llv[512][4096] -> sgnT[4096][512] (+-1.0f), column pos-counts
__global__ void k_sgn_transpose(const float* __restrict__ llv, float* __restrict__ sgnT,
                                int* __restrict__ colcnt){
  __shared__ float tile[64][65];
  int ti = blockIdx.x, tl = blockIdx.y;          // 64 x 8 tiles of 64x64
  int tid = threadIdx.x;                          // 256
  int ii = tid & 63, rr = tid >> 6;
  int i0 = ti*64, l0 = tl*64;
  int cnt = 0;
  #pragma unroll
  for (int r = 0; r < 16; ++r){
    int l = l0 + rr*16 + r;
    float v = llv[l*4096 + i0 + ii];
    bool pos = (v >= 0.0f);
    cnt += pos ? 1 : 0;
    tile[ii][rr*16 + r] = pos ? 1.0f : -1.0f;
  }
  atomicAdd(&colcnt[i0 + ii], cnt);
  __syncthreads();
  #pragma unroll
  for (int r = 0; r < 16; ++r){
    int il = rr*16 + r;
    sgnT[(i0 + il)*512 + l0 + ii] = tile[il][ii];
  }
}

// ---- k2: pack x rows to bits (bit=1 <=> x=+1)
__global__ void k_xbits(const float* __restrict__ llv, unsigned long long* __restrict__ xbits){
  int w = threadIdx.x >> 6, lane = threadIdx.x & 63;
  int l = blockIdx.x*4 + w;
  unsigned long long myword = 0;
  for (int c = 0; c < 64; ++c){
    float v = llv[l*4096 + c*64 + lane];
    unsigned long long b = __ballot(v >= 0.0f);
    if (c == lane) myword = b;
  }
  xbits[l*64 + lane] = myword;
}

// ---- k3: p~ init: p0[l] = sum_j sign(llv[l,j]) * s0[j]
__global__ void k_pinit(const float* __restrict__ llv, const float* __restrict__ s0,
                        float* __restrict__ p0){
  int l = blockIdx.x, lane = threadIdx.x;
  float acc = 0.0f;
  for (int c = 0; c < 64; ++c){
    float v = llv[l*4096 + c*64 + lane];
    float sg = (v >= 0.0f) ? 1.0f : -1.0f;
    acc = fmaf(sg, s0[c*64 + lane], acc);
  }
  float tot = wave_allsum(acc);
  if (lane == 0) p0[l] = tot;
}

// ---- k4a: rho from column counts (exact: integers, /2^21)
__global__ void k_rho(const int* __restrict__ colcnt, float* __restrict__ hdr){
  __shared__ int sh[256];
  int tid = threadIdx.x;
  int s = 0;
  for (int k = tid; k < 4096; k += 256) s += colcnt[k];
  sh[tid] = s; __syncthreads();
  for (int st = 128; st > 0; st >>= 1){
    if (tid < st) sh[tid] += sh[tid + st];
    __syncthreads();
  }
  if (tid == 0){
    int num = 2*sh[0] - 2097152;          // sum of x entries, |num| < 2^21 -> exact
    hdr[0] = (float)num * (1.0f/2097152.0f);
  }
}

// ---- k4b: per-step constants {f, A, dp, c}
__global__ void k_const(const int* __restrict__ colcnt, const float* __restrict__ hdr,
                        const float* __restrict__ s0, float4* __restrict__ cst){
  int i = blockIdx.x*256 + threadIdx.x;
  float rho = hdr[0];
  float c  = (float)(2*colcnt[i] - 512);  // exact integer
  float r2 = rho*rho;
  float q  = 512.0f + 512.0f*r2 - 2.0f*rho*c;
  float s  = s0[i];
  float4 o;
  o.x = q * s;                 // f_i
  o.y = rho*c - 512.0f*r2;     // A_i
  o.z = 1.0f - s;              // dp (d if v>=0) ; dm = dp - 2
  o.w = c;                     // c_i
  cst[i] = o;
}

// ---- k5: the sequential sweep, one wave. 8 p~ per lane.
__device__ __forceinline__ void pref(const float4* __restrict__ sg4,
                                     const float4* __restrict__ cst4,
                                     int blk, int lane,
                                     float4 (&buf)[8][2], float4 (&cc)[8]){
  #pragma unroll
  for (int k = 0; k < 8; ++k){
    int idx = (blk*8 + k)*128 + lane*2;
    buf[k][0] = sg4[idx];
    buf[k][1] = sg4[idx + 1];
    cc[k]     = cst4[blk*8 + k];
  }
}

#define PROCBLK(BUF, CC, BLK) do {                                              \
  const int bitbase = ((BLK) & 7) * 8;                                          \
  _Pragma("unroll")                                                             \
  for (int k = 0; k < 8; ++k){                                                  \
    float4 x0 = BUF[k][0], x1 = BUF[k][1];                                      \
    float4 c  = CC[k];                                                          \
    float m = x0.x*p[0] + x0.y*p[1] + x0.z*p[2] + x0.w*p[3]                     \
            + x1.x*p[4] + x1.y*p[5] + x1.z*p[6] + x1.w*p[7];                    \
    float S = wave_allsum(m);                                                   \
    float v = fmaf(-rho, P, S - c.x);                                           \
    v = fmaf(-c.y, T, v);                                                       \
    bool flag = (v >= 0.0f);                                                    \
    float d = flag ? c.z : (c.z - 2.0f);                                        \
    p[0] = fmaf(x0.x, d, p[0]); p[1] = fmaf(x0.y, d, p[1]);                     \
    p[2] = fmaf(x0.z, d, p[2]); p[3] = fmaf(x0.w, d, p[3]);                     \
    p[4] = fmaf(x1.x, d, p[4]); p[5] = fmaf(x1.y, d, p[5]);                     \
    p[6] = fmaf(x1.z, d, p[6]); p[7] = fmaf(x1.w, d, p[7]);                     \
    P = fmaf(d, c.w, P);                                                        \
    T += d;                                                                     \
    bits |= ((unsigned long long)(flag ? 1 : 0)) << (bitbase + k);              \
  }                                                                             \
  if ((((BLK) & 7) == 7)){ if (lane == 0) sbits[(BLK) >> 3] = bits; bits = 0ull; } \
} while (0)

__global__ __launch_bounds__(64, 1)
void k_sweep(const float* __restrict__ sgnT, const float4* __restrict__ cst4,
             const float* __restrict__ p0, const float* __restrict__ s0,
             const float* __restrict__ hdr, unsigned long long* __restrict__ sbits){
  int lane = threadIdx.x;
  float rho = hdr[0];
  const float4* sg4 = (const float4*)sgnT;

  // load p~ (8 per lane, contiguous): indices lane*8 .. lane*8+7
  const float4* p04 = (const float4*)p0;
  float4 pa = p04[lane*2], pb = p04[lane*2 + 1];
  float p[8] = {pa.x, pa.y, pa.z, pa.w, pb.x, pb.y, pb.z, pb.w};

  float P = wave_allsum(p[0]+p[1]+p[2]+p[3]+p[4]+p[5]+p[6]+p[7]);
  float t = 0.0f;
  for (int c = 0; c < 64; ++c) t += s0[c*64 + lane];
  float T = wave_allsum(t);

  float4 bufA[8][2], bufB[8][2], ccA[8], ccB[8];
  pref(sg4, cst4, 0, lane, bufA, ccA);
  unsigned long long bits = 0ull;

  for (int bb = 0; bb < 256; ++bb){
    int b0 = bb*2;
    pref(sg4, cst4, b0 + 1, lane, bufB, ccB);   // prefetch next while computing
    PROCBLK(bufA, ccA, b0);
    int nb = (b0 + 2 < 512) ? (b0 + 2) : 511;
    pref(sg4, cst4, nb, lane, bufA, ccA);
    PROCBLK(bufB, ccB, b0 + 1);
  }
}

// ---- k6: exact integer scores + argmax one-hot
__global__ void k_scores(const unsigned long long* __restrict__ xbits,
                         const unsigned long long* __restrict__ sbits,
                         float* __restrict__ out){
  __shared__ unsigned long long sb[64];
  __shared__ int bestkey;
  int tid = threadIdx.x;  // 512
  if (tid < 64) sb[tid] = sbits[tid];
  if (tid == 0) bestkey = -1;
  __syncthreads();
  int acc = 0;
  #pragma unroll
  for (int w = 0; w < 64; ++w)
    acc += __popcll(xbits[tid*64 + w] ^ sb[w]);
  int dot = 4096 - 2*acc;                 // exact
  int ad  = dot < 0 ? -dot : dot;
  int key = (ad << 10) | (511 - tid);     // tie -> smaller index wins (np.argmax)
  atomicMax(&bestkey, key);
  __syncthreads();
  int bl = 511 - (bestkey & 1023);
  float val = (float)(bestkey >> 10) * (1.0f/4096.0f);  // exact (pow2 scale)
  out[tid] = (tid == bl) ? val : 0.0f;
}

extern "C" void kernel_launch(void* const* d_in, const int* in_sizes, int n_in,
                              void* d_out, int out_size, void* d_ws, size_t ws_size,
                              hipStream_t stream){
  const float* s0  = (const float*)d_in[0];   // [4096]
  const float* llv = (const float*)d_in[1];   // [512][4096]
  float* out = (float*)d_out;                 // [512]
  char* ws = (char*)d_ws;                     // needs ~8.8 MB

  float* sgnT  = (float*)(ws + WS_SGN_OFF);
  float4* cst  = (float4*)(ws + WS_CST_OFF);
  unsigned long long* xbits = (unsigned long long*)(ws + WS_XBITS_OFF);
  float* p0    = (float*)(ws + WS_P0_OFF);
  unsigned long long* sbits = (unsigned long long*)(ws + WS_SBITS_OFF);
  int* colcnt  = (int*)(ws + WS_CNT_OFF);
  float* hdr   = (float*)(ws + WS_HDR_OFF);

  hipMemsetAsync(ws + WS_CNT_OFF, 0, 4096*sizeof(int), stream);
  k_sgn_transpose<<<dim3(64, 8), 256, 0, stream>>>(llv, sgnT, colcnt);
  k_xbits<<<128, 256, 0, stream>>>(llv, xbits);
  k_pinit<<<512, 64, 0, stream>>>(llv, s0, p0);
  k_rho<<<1, 256, 0, stream>>>(colcnt, hdr);
  k_const<<<16, 256, 0, stream>>>(colcnt, hdr, s0, cst);
  k_sweep<<<1, 64, 0, stream>>>(sgnT, cst, p0, s0, hdr, sbits);
  k_scores<<<1, 512, 0, stream>>>(xbits, sbits, out);
}

// Round 2
// 260.901 us; speedup vs baseline: 2.3700x; 2.3700x over previous
//
#include <hip/hip_runtime.h>
#include <hip/hip_bf16.h>

// Hopfield forward, blocked factored Gauss-Seidel.
// Block of 64 steps: v_t(base) = S_t - f_t - rho*P - A_t*T - baseCorr_t,
// in-block: v_t += sigma_j * K[t,j], K precomputed (popcount Gram + rho terms).
// p update per block: p_l += (64 - 2 popc(x_l ^ sigma)) - U[b][l].

#define OFF_COLB   0u                       // u64 [8][4096]  colbitsP (bits over l)
#define OFF_XBITS  (256u<<10)               // u64 [512][64]  row bits (bits over i)
#define OFF_XBW    (512u<<10)               // u64 [64][512]  xbitsW (i-block major)
#define OFF_KF     (768u<<10)               // f32 [64][64][64] Kf : 1 MB
#define OFF_BCORR  (1792u<<10)              // f32 [4096] baseCorr
#define OFF_U      (1808u<<10)              // f32 [64][512] U
#define OFF_CST    (1936u<<10)              // float4 [4096] {f, A, dp, c}
#define OFF_P0     (2000u<<10)              // f32 [512]
#define OFF_SBITS  (2002u<<10)              // u64 [64]
#define OFF_CNT    (2003u<<10)              // int [4096]
#define OFF_HDR    (2019u<<10)              // f32 [16]
#define OFF_BS0    (2020u<<10)              // f32 [64] blkS0
#define OFF_BS0C   (2021u<<10)              // f32 [64] blkS0C

template<int CTRL, int RMASK>
__device__ __forceinline__ float dpp_add(float x){
  int t = __builtin_amdgcn_update_dpp(0, __float_as_int(x), CTRL, RMASK, 0xf, true);
  return x + __int_as_float(t);
}
__device__ __forceinline__ float wave_allsum(float x){
  x = dpp_add<0x111,0xf>(x);
  x = dpp_add<0x112,0xf>(x);
  x = dpp_add<0x114,0xf>(x);
  x = dpp_add<0x118,0xf>(x);
  x = dpp_add<0x142,0xa>(x);
  x = dpp_add<0x143,0xc>(x);
  return __int_as_float(__builtin_amdgcn_readlane(__float_as_int(x), 63));
}

// ---- row bits: xbits[l][w] (bit j of word w = sign of column w*64+j), plus transposed-block layout
__global__ void k_xbits(const float* __restrict__ llv, unsigned long long* __restrict__ xbits,
                        unsigned long long* __restrict__ xbitsW){
  int w = threadIdx.x >> 6, lane = threadIdx.x & 63;
  int l = blockIdx.x*4 + w;
  unsigned long long myword = 0;
  for (int c = 0; c < 64; ++c){
    float v = llv[(size_t)l*4096 + c*64 + lane];
    unsigned long long b = __ballot(v >= 0.0f);
    if (c == lane) myword = b;
  }
  xbits[(size_t)l*64 + lane] = myword;
  xbitsW[(size_t)lane*512 + l] = myword;
}

// ---- bit transpose: colbitsP[wl][i] = bits over labels l = wl*64..wl*64+63 for column i
__global__ void k_bitT(const unsigned long long* __restrict__ xbits,
                       unsigned long long* __restrict__ colbitsP){
  int li = blockIdx.x;   // 0..7  (l-word)
  int ii = blockIdx.y;   // 0..63 (i-word)
  int lane = threadIdx.x;
  unsigned long long w = xbits[(size_t)(li*64 + lane)*64 + ii];
  unsigned long long myw = 0;
  for (int j = 0; j < 64; ++j){
    unsigned long long b = __ballot((w >> j) & 1ull);
    if (j == lane) myw = b;
  }
  colbitsP[(size_t)li*4096 + ii*64 + lane] = myw;
}

// ---- column positive counts from colbitsP
__global__ void k_colc(const unsigned long long* __restrict__ colbitsP, int* __restrict__ colcnt){
  int i = blockIdx.x*256 + threadIdx.x;
  int c = 0;
  #pragma unroll
  for (int wl = 0; wl < 8; ++wl) c += __popcll(colbitsP[(size_t)wl*4096 + i]);
  colcnt[i] = c;
}

// ---- rho (exact integer)
__global__ void k_rho(const int* __restrict__ colcnt, float* __restrict__ hdr){
  __shared__ int sh[256];
  int tid = threadIdx.x;
  int s = 0;
  for (int k = tid; k < 4096; k += 256) s += colcnt[k];
  sh[tid] = s; __syncthreads();
  for (int st = 128; st > 0; st >>= 1){
    if (tid < st) sh[tid] += sh[tid + st];
    __syncthreads();
  }
  if (tid == 0){
    int num = 2*sh[0] - 2097152;
    hdr[0] = (float)num * (1.0f/2097152.0f);
  }
}

// ---- per-step constants {f, A, dp, c}
__global__ void k_const(const int* __restrict__ colcnt, const float* __restrict__ hdr,
                        const float* __restrict__ s0, float4* __restrict__ cst){
  int i = blockIdx.x*256 + threadIdx.x;
  float rho = hdr[0];
  float c  = (float)(2*colcnt[i] - 512);
  float r2 = rho*rho;
  float q  = 512.0f + 512.0f*r2 - 2.0f*rho*c;
  float s  = s0[i];
  float4 o;
  o.x = q * s;
  o.y = rho*c - 512.0f*r2;
  o.z = 1.0f - s;
  o.w = c;
  cst[i] = o;
}

// ---- diagonal K blocks (64x64 per i-block) + baseCorr + block s0 sums
__global__ void k_kdiag(const unsigned long long* __restrict__ colbitsP,
                        const float4* __restrict__ cst, const float* __restrict__ s0,
                        const float* __restrict__ hdr,
                        float* __restrict__ Kf, float* __restrict__ baseCorr,
                        float* __restrict__ blkS0, float* __restrict__ blkS0C){
  __shared__ unsigned long long cb[8][64];
  __shared__ float Kl[64][64];
  __shared__ float cs[64], ss[64];
  int b = blockIdx.x, i0 = b*64, tid = threadIdx.x;  // 256 threads
  for (int k = tid; k < 512; k += 256)
    cb[k>>6][k&63] = colbitsP[(size_t)(k>>6)*4096 + i0 + (k&63)];
  if (tid < 64){ cs[tid] = cst[i0+tid].w; ss[tid] = s0[i0+tid]; }
  __syncthreads();
  float rho = hdr[0];
  float r2t = 512.0f*rho*rho;
  #pragma unroll
  for (int k = 0; k < 16; ++k){
    int q = tid*16 + k;
    int t = q >> 6, j = q & 63;
    int acc = 0;
    #pragma unroll
    for (int wl = 0; wl < 8; ++wl) acc += __popcll(cb[wl][t] ^ cb[wl][j]);
    float G = (float)(512 - 2*acc);
    float kf = G - rho*(cs[t]+cs[j]) + r2t;
    Kl[t][j] = kf;
    Kf[(size_t)b*4096 + q] = kf;
  }
  __syncthreads();
  if (tid < 64){
    float bc = 0.0f;
    for (int j = 0; j < tid; ++j) bc = fmaf(ss[j], Kl[tid][j], bc);
    baseCorr[i0 + tid] = bc;
  }
  if (tid == 64){
    float a = 0.0f, b2 = 0.0f;
    for (int j = 0; j < 64; ++j){ a += ss[j]; b2 = fmaf(ss[j], cs[j], b2); }
    blkS0[b] = a; blkS0C[b] = b2;
  }
}

// ---- U[b][l] = sum_j s0[i0+j] * x[l][i0+j]
__global__ void k_u(const unsigned long long* __restrict__ xbits, const float* __restrict__ s0,
                    float* __restrict__ U){
  __shared__ float s0l[64];
  int b = blockIdx.x, l = threadIdx.x;  // 512 threads
  if (l < 64) s0l[l] = s0[b*64 + l];
  __syncthreads();
  unsigned long long w = xbits[(size_t)l*64 + b];
  unsigned int lo = (unsigned)w, hi = (unsigned)(w >> 32);
  unsigned int nlo = ~lo, nhi = ~hi;
  float acc = 0.0f;
  #pragma unroll
  for (int j = 0; j < 32; ++j){
    unsigned int m = (nlo << (31-j)) & 0x80000000u;
    acc += __uint_as_float(__float_as_uint(s0l[j]) ^ m);
  }
  #pragma unroll
  for (int j = 0; j < 32; ++j){
    unsigned int m = (nhi << (31-j)) & 0x80000000u;
    acc += __uint_as_float(__float_as_uint(s0l[32+j]) ^ m);
  }
  U[(size_t)b*512 + l] = acc;
}

// ---- p0[l] = sum_j sign(llv[l,j]) * s0[j]
__global__ void k_pinit(const float* __restrict__ llv, const float* __restrict__ s0,
                        float* __restrict__ p0){
  int l = blockIdx.x, lane = threadIdx.x;
  float acc = 0.0f;
  for (int c = 0; c < 64; ++c){
    float v = llv[(size_t)l*4096 + c*64 + lane];
    float sg = (v >= 0.0f) ? 1.0f : -1.0f;
    acc = fmaf(sg, s0[c*64 + lane], acc);
  }
  float tot = wave_allsum(acc);
  if (lane == 0) p0[l] = tot;
}

// ---- the blocked sequential sweep: 1 block, 512 threads (8 waves)
__global__ __launch_bounds__(512, 1)
void k_sweep2(const unsigned long long* __restrict__ colbitsP,
              const unsigned long long* __restrict__ xbitsW,
              const float* __restrict__ Kf, const float* __restrict__ baseCorr,
              const float* __restrict__ blkS0, const float* __restrict__ blkS0C,
              const float* __restrict__ U, const float4* __restrict__ cst,
              const float* __restrict__ p0, const float* __restrict__ s0,
              const float* __restrict__ hdr, unsigned long long* __restrict__ sbits)
{
  __shared__ float p[512];
  __shared__ float part[8][64];
  __shared__ float red[512];
  __shared__ unsigned long long sig;
  int tid = threadIdx.x, g = tid >> 6, t = tid & 63;
  float rho = hdr[0];

  // init p, P, T
  p[tid] = p0[tid];
  red[tid] = p0[tid];
  __syncthreads();
  for (int st = 256; st > 0; st >>= 1){ if (tid < st) red[tid] += red[tid+st]; __syncthreads(); }
  float Preg = red[0];
  __syncthreads();
  { float a = 0.0f; for (int k = 0; k < 8; ++k) a += s0[tid*8 + k]; red[tid] = a; }
  __syncthreads();
  for (int st = 256; st > 0; st >>= 1){ if (tid < st) red[tid] += red[tid+st]; __syncthreads(); }
  float Treg = red[0];
  __syncthreads();

  for (int b = 0; b < 64; ++b){
    int i0 = b*64;
    // wave0 prefetches its K row (latency hides under phase 1)
    float kv[64];
    if (g == 0){
      const float4* K4 = (const float4*)(Kf + (size_t)b*4096 + t*64);
      #pragma unroll
      for (int c = 0; c < 16; ++c){
        float4 x4 = K4[c];
        kv[4*c] = x4.x; kv[4*c+1] = x4.y; kv[4*c+2] = x4.z; kv[4*c+3] = x4.w;
      }
    }
    // phase 1: S_t partials, wave g covers labels 64g..64g+63
    unsigned long long w = colbitsP[(size_t)g*4096 + i0 + t];
    unsigned int lo = (unsigned)w, hi = (unsigned)(w >> 32);
    unsigned int nlo = ~lo, nhi = ~hi;
    float acc = 0.0f;
    #pragma unroll
    for (int j = 0; j < 32; ++j){
      unsigned int m = (nlo << (31-j)) & 0x80000000u;
      acc += __uint_as_float(__float_as_uint(p[g*64 + j]) ^ m);
    }
    #pragma unroll
    for (int j = 0; j < 32; ++j){
      unsigned int m = (nhi << (31-j)) & 0x80000000u;
      acc += __uint_as_float(__float_as_uint(p[g*64 + 32 + j]) ^ m);
    }
    part[g][t] = acc;
    __syncthreads();                              // B1

    if (g == 0){
      float S = 0.0f;
      #pragma unroll
      for (int gg = 0; gg < 8; ++gg) S += part[gg][t];
      float4 cc = cst[i0 + t];
      float v = S - cc.x - rho*Preg - cc.y*Treg - baseCorr[i0 + t];
      // phase 2: 64 sequential steps, readlane broadcast + sign-xor FMA-free update
      unsigned long long sg_ = 0ull;
      #pragma unroll
      for (int j = 0; j < 64; ++j){
        int vi = __builtin_amdgcn_readlane(__float_as_int(v), j);
        unsigned int m = ((unsigned)vi) & 0x80000000u;
        sg_ |= ((unsigned long long)((~((unsigned)vi)) >> 31)) << j;
        v += __uint_as_float(__float_as_uint(kv[j]) ^ m);
      }
      if (t == 0){ sig = sg_; sbits[b] = sg_; }
      // P, T updates (wave0-only registers)
      float sv = ((sg_ >> t) & 1ull) ? cc.w : -cc.w;
      float sc = wave_allsum(sv);
      int pcs = __popcll(sg_);
      Preg += sc - blkS0C[b];
      Treg += (float)(2*pcs - 64) - blkS0[b];
    }
    __syncthreads();                              // B2
    // phase 3: p update, one label per thread
    unsigned long long xw = xbitsW[(size_t)b*512 + tid];
    unsigned long long sgv = sig;
    int pc = __popcll(xw ^ sgv);
    p[tid] = p[tid] + (float)(64 - 2*pc) - U[(size_t)b*512 + tid];
    __syncthreads();                              // B3
  }
}

// ---- exact integer scores + argmax one-hot
__global__ void k_scores(const unsigned long long* __restrict__ xbits,
                         const unsigned long long* __restrict__ sbits,
                         float* __restrict__ out){
  __shared__ unsigned long long sb[64];
  __shared__ int bestkey;
  int tid = threadIdx.x;  // 512
  if (tid < 64) sb[tid] = sbits[tid];
  if (tid == 0) bestkey = -1;
  __syncthreads();
  int acc = 0;
  #pragma unroll
  for (int w = 0; w < 64; ++w)
    acc += __popcll(xbits[(size_t)tid*64 + w] ^ sb[w]);
  int dot = 4096 - 2*acc;
  int ad  = dot < 0 ? -dot : dot;
  int key = (ad << 10) | (511 - tid);
  atomicMax(&bestkey, key);
  __syncthreads();
  int bl = 511 - (bestkey & 1023);
  float val = (float)(bestkey >> 10) * (1.0f/4096.0f);
  out[tid] = (tid == bl) ? val : 0.0f;
}

extern "C" void kernel_launch(void* const* d_in, const int* in_sizes, int n_in,
                              void* d_out, int out_size, void* d_ws, size_t ws_size,
                              hipStream_t stream){
  const float* s0  = (const float*)d_in[0];   // [4096]
  const float* llv = (const float*)d_in[1];   // [512][4096]
  float* out = (float*)d_out;                 // [512]
  char* ws = (char*)d_ws;

  unsigned long long* colbitsP = (unsigned long long*)(ws + OFF_COLB);
  unsigned long long* xbits    = (unsigned long long*)(ws + OFF_XBITS);
  unsigned long long* xbitsW   = (unsigned long long*)(ws + OFF_XBW);
  float*  Kf    = (float*)(ws + OFF_KF);
  float*  bcorr = (float*)(ws + OFF_BCORR);
  float*  U     = (float*)(ws + OFF_U);
  float4* cst   = (float4*)(ws + OFF_CST);
  float*  p0    = (float*)(ws + OFF_P0);
  unsigned long long* sbits = (unsigned long long*)(ws + OFF_SBITS);
  int*    colcnt = (int*)(ws + OFF_CNT);
  float*  hdr   = (float*)(ws + OFF_HDR);
  float*  bS0   = (float*)(ws + OFF_BS0);
  float*  bS0C  = (float*)(ws + OFF_BS0C);

  k_xbits<<<128, 256, 0, stream>>>(llv, xbits, xbitsW);
  k_bitT<<<dim3(8, 64), 64, 0, stream>>>(xbits, colbitsP);
  k_colc<<<16, 256, 0, stream>>>(colbitsP, colcnt);
  k_rho<<<1, 256, 0, stream>>>(colcnt, hdr);
  k_const<<<16, 256, 0, stream>>>(colcnt, hdr, s0, cst);
  k_kdiag<<<64, 256, 0, stream>>>(colbitsP, cst, s0, hdr, Kf, bcorr, bS0, bS0C);
  k_u<<<64, 512, 0, stream>>>(xbits, s0, U);
  k_pinit<<<512, 64, 0, stream>>>(llv, s0, p0);
  k_sweep2<<<1, 512, 0, stream>>>(colbitsP, xbitsW, Kf, bcorr, bS0, bS0C, U, cst, p0, s0, hdr, sbits);
  k_scores<<<1, 512, 0, stream>>>(xbits, sbits, out);
}

// Round 5
// 243.790 us; speedup vs baseline: 2.5364x; 1.0702x over previous
//
#include <hip/hip_runtime.h>
#include <hip/hip_bf16.h>

// Hopfield forward, blocked factored Gauss-Seidel (round-2 structure, passing),
// single change: wave0's K row in 16 named float4 REGISTERS (was scratch kv[64]),
// phase-2 fully unrolled; pure global loads hoisted to top of block body.

#define OFF_COLB   0u                       // u64 [8][4096]  colbitsP (bits over l)
#define OFF_XBITS  (256u<<10)               // u64 [512][64]  row bits (bits over i)
#define OFF_XBW    (512u<<10)               // u64 [64][512]  xbitsW (i-block major)
#define OFF_KF     (768u<<10)               // f32 [64][64][64] Kf : 1 MB
#define OFF_BCORR  (1792u<<10)              // f32 [4096] baseCorr
#define OFF_U      (1808u<<10)              // f32 [64][512] U
#define OFF_CST    (1936u<<10)              // float4 [4096] {f, A, dp, c}
#define OFF_P0     (2000u<<10)              // f32 [512]
#define OFF_SBITS  (2002u<<10)              // u64 [64]
#define OFF_CNT    (2003u<<10)              // int [4096]
#define OFF_HDR    (2019u<<10)              // f32 [16]  (rho)
#define OFF_BS0    (2020u<<10)              // f32 [64] blkS0
#define OFF_BS0C   (2021u<<10)              // f32 [64] blkS0C

template<int CTRL, int RMASK>
__device__ __forceinline__ float dpp_add(float x){
  int t = __builtin_amdgcn_update_dpp(0, __float_as_int(x), CTRL, RMASK, 0xf, true);
  return x + __int_as_float(t);
}
__device__ __forceinline__ float wave_allsum(float x){
  x = dpp_add<0x111,0xf>(x);
  x = dpp_add<0x112,0xf>(x);
  x = dpp_add<0x114,0xf>(x);
  x = dpp_add<0x118,0xf>(x);
  x = dpp_add<0x142,0xa>(x);
  x = dpp_add<0x143,0xc>(x);
  return __int_as_float(__builtin_amdgcn_readlane(__float_as_int(x), 63));
}

// ---- row bits + transposed-block layout
__global__ void k_xbits(const float* __restrict__ llv, unsigned long long* __restrict__ xbits,
                        unsigned long long* __restrict__ xbitsW){
  int w = threadIdx.x >> 6, lane = threadIdx.x & 63;
  int l = blockIdx.x*4 + w;
  unsigned long long myword = 0;
  for (int c = 0; c < 64; ++c){
    float v = llv[(size_t)l*4096 + c*64 + lane];
    unsigned long long b = __ballot(v >= 0.0f);
    if (c == lane) myword = b;
  }
  xbits[(size_t)l*64 + lane] = myword;
  xbitsW[(size_t)lane*512 + l] = myword;
}

// ---- bit transpose: colbitsP[wl][i] = bits over labels for column i
__global__ void k_bitT(const unsigned long long* __restrict__ xbits,
                       unsigned long long* __restrict__ colbitsP){
  int li = blockIdx.x;   // 0..7
  int ii = blockIdx.y;   // 0..63
  int lane = threadIdx.x;
  unsigned long long w = xbits[(size_t)(li*64 + lane)*64 + ii];
  unsigned long long myw = 0;
  for (int j = 0; j < 64; ++j){
    unsigned long long b = __ballot((w >> j) & 1ull);
    if (j == lane) myw = b;
  }
  colbitsP[(size_t)li*4096 + ii*64 + lane] = myw;
}

// ---- column positive counts
__global__ void k_colc(const unsigned long long* __restrict__ colbitsP, int* __restrict__ colcnt){
  int i = blockIdx.x*256 + threadIdx.x;
  int c = 0;
  #pragma unroll
  for (int wl = 0; wl < 8; ++wl) c += __popcll(colbitsP[(size_t)wl*4096 + i]);
  colcnt[i] = c;
}

// ---- rho (exact integer)
__global__ void k_rho(const int* __restrict__ colcnt, float* __restrict__ hdr){
  __shared__ int sh[256];
  int tid = threadIdx.x;
  int s = 0;
  for (int k = tid; k < 4096; k += 256) s += colcnt[k];
  sh[tid] = s; __syncthreads();
  for (int st = 128; st > 0; st >>= 1){
    if (tid < st) sh[tid] += sh[tid + st];
    __syncthreads();
  }
  if (tid == 0){
    int num = 2*sh[0] - 2097152;
    hdr[0] = (float)num * (1.0f/2097152.0f);
  }
}

// ---- per-step constants {f, A, dp, c}
__global__ void k_const(const int* __restrict__ colcnt, const float* __restrict__ hdr,
                        const float* __restrict__ s0, float4* __restrict__ cst){
  int i = blockIdx.x*256 + threadIdx.x;
  float rho = hdr[0];
  float c  = (float)(2*colcnt[i] - 512);
  float r2 = rho*rho;
  float q  = 512.0f + 512.0f*r2 - 2.0f*rho*c;
  float s  = s0[i];
  float4 o;
  o.x = q * s;
  o.y = rho*c - 512.0f*r2;
  o.z = 1.0f - s;
  o.w = c;
  cst[i] = o;
}

// ---- diagonal K blocks + baseCorr + block s0 sums
__global__ void k_kdiag(const unsigned long long* __restrict__ colbitsP,
                        const float4* __restrict__ cst, const float* __restrict__ s0,
                        const float* __restrict__ hdr,
                        float* __restrict__ Kf, float* __restrict__ baseCorr,
                        float* __restrict__ blkS0, float* __restrict__ blkS0C){
  __shared__ unsigned long long cb[8][64];
  __shared__ float Kl[64][64];
  __shared__ float cs[64], ss[64];
  int b = blockIdx.x, i0 = b*64, tid = threadIdx.x;  // 256 threads
  for (int k = tid; k < 512; k += 256)
    cb[k>>6][k&63] = colbitsP[(size_t)(k>>6)*4096 + i0 + (k&63)];
  if (tid < 64){ cs[tid] = cst[i0+tid].w; ss[tid] = s0[i0+tid]; }
  __syncthreads();
  float rho = hdr[0];
  float r2t = 512.0f*rho*rho;
  #pragma unroll
  for (int k = 0; k < 16; ++k){
    int q = tid*16 + k;
    int t = q >> 6, j = q & 63;
    int acc = 0;
    #pragma unroll
    for (int wl = 0; wl < 8; ++wl) acc += __popcll(cb[wl][t] ^ cb[wl][j]);
    float G = (float)(512 - 2*acc);
    float kf = G - rho*(cs[t]+cs[j]) + r2t;
    Kl[t][j] = kf;
    Kf[(size_t)b*4096 + q] = kf;
  }
  __syncthreads();
  if (tid < 64){
    float bc = 0.0f;
    for (int j = 0; j < tid; ++j) bc = fmaf(ss[j], Kl[tid][j], bc);
    baseCorr[i0 + tid] = bc;
  }
  if (tid == 64){
    float a = 0.0f, b2 = 0.0f;
    for (int j = 0; j < 64; ++j){ a += ss[j]; b2 = fmaf(ss[j], cs[j], b2); }
    blkS0[b] = a; blkS0C[b] = b2;
  }
}

// ---- U[b][l] = sum_j s0[i0+j] * x[l][i0+j]
__global__ void k_u(const unsigned long long* __restrict__ xbits, const float* __restrict__ s0,
                    float* __restrict__ U){
  __shared__ float s0l[64];
  int b = blockIdx.x, l = threadIdx.x;  // 512 threads
  if (l < 64) s0l[l] = s0[b*64 + l];
  __syncthreads();
  unsigned long long w = xbits[(size_t)l*64 + b];
  unsigned int lo = (unsigned)w, hi = (unsigned)(w >> 32);
  unsigned int nlo = ~lo, nhi = ~hi;
  float acc = 0.0f;
  #pragma unroll
  for (int j = 0; j < 32; ++j){
    unsigned int m = (nlo << (31-j)) & 0x80000000u;
    acc += __uint_as_float(__float_as_uint(s0l[j]) ^ m);
  }
  #pragma unroll
  for (int j = 0; j < 32; ++j){
    unsigned int m = (nhi << (31-j)) & 0x80000000u;
    acc += __uint_as_float(__float_as_uint(s0l[32+j]) ^ m);
  }
  U[(size_t)b*512 + l] = acc;
}

// ---- p0[l] = sum_j sign(llv[l,j]) * s0[j]
__global__ void k_pinit(const float* __restrict__ llv, const float* __restrict__ s0,
                        float* __restrict__ p0){
  int l = blockIdx.x, lane = threadIdx.x;
  float acc = 0.0f;
  for (int c = 0; c < 64; ++c){
    float v = llv[(size_t)l*4096 + c*64 + lane];
    float sg = (v >= 0.0f) ? 1.0f : -1.0f;
    acc = fmaf(sg, s0[c*64 + lane], acc);
  }
  float tot = wave_allsum(acc);
  if (lane == 0) p0[l] = tot;
}

// ---- named-register K row + unrolled serial chain (the ONLY change vs round 2)
#define K_DECL(P) float4 P##0,P##1,P##2,P##3,P##4,P##5,P##6,P##7,P##8,P##9,P##10,P##11,P##12,P##13,P##14,P##15;
#define K_LOAD(P, BIDX) { const float4* kp_ = (const float4*)(Kf + (size_t)(BIDX)*4096 + t*64); \
  P##0=kp_[0];  P##1=kp_[1];  P##2=kp_[2];  P##3=kp_[3];  \
  P##4=kp_[4];  P##5=kp_[5];  P##6=kp_[6];  P##7=kp_[7];  \
  P##8=kp_[8];  P##9=kp_[9];  P##10=kp_[10];P##11=kp_[11];\
  P##12=kp_[12];P##13=kp_[13];P##14=kp_[14];P##15=kp_[15]; }

// serial step: sigma_J = sign(v at lane J); v += sigma_J * K[t][J]
// fmaf(+-1, K, v) is bit-identical to round 2's  v += (K ^ signbit).
#define STP(KVAL, J) { \
  int vi_ = __builtin_amdgcn_readlane(__float_as_int(v), (J)); \
  float sg2_ = (vi_ < 0) ? -1.0f : 1.0f; \
  sg_ |= ((unsigned long long)((~((unsigned)vi_)) >> 31)) << (J); \
  v = fmaf(sg2_, (KVAL), v); }
#define STP4(Q, J0) STP(Q.x,(J0)+0) STP(Q.y,(J0)+1) STP(Q.z,(J0)+2) STP(Q.w,(J0)+3)
#define PH2(P) STP4(P##0,0)  STP4(P##1,4)  STP4(P##2,8)  STP4(P##3,12) \
               STP4(P##4,16) STP4(P##5,20) STP4(P##6,24) STP4(P##7,28) \
               STP4(P##8,32) STP4(P##9,36) STP4(P##10,40) STP4(P##11,44) \
               STP4(P##12,48) STP4(P##13,52) STP4(P##14,56) STP4(P##15,60)

// ---- the blocked sequential sweep: 1 block, 512 threads (8 waves) — round-2 structure
__global__ __launch_bounds__(512, 1)
void k_sweep2(const unsigned long long* __restrict__ colbitsP,
              const unsigned long long* __restrict__ xbitsW,
              const float* __restrict__ Kf, const float* __restrict__ baseCorr,
              const float* __restrict__ blkS0, const float* __restrict__ blkS0C,
              const float* __restrict__ U, const float4* __restrict__ cst,
              const float* __restrict__ p0, const float* __restrict__ s0,
              const float* __restrict__ hdr, unsigned long long* __restrict__ sbits)
{
  __shared__ float p[512];
  __shared__ float part[8][64];
  __shared__ float red[512];
  __shared__ unsigned long long sig;
  int tid = threadIdx.x, g = tid >> 6, t = tid & 63;
  float rho = hdr[0];

  // init p, P, T  (verbatim round 2)
  p[tid] = p0[tid];
  red[tid] = p0[tid];
  __syncthreads();
  for (int st = 256; st > 0; st >>= 1){ if (tid < st) red[tid] += red[tid+st]; __syncthreads(); }
  float Preg = red[0];
  __syncthreads();
  { float a = 0.0f; for (int k = 0; k < 8; ++k) a += s0[tid*8 + k]; red[tid] = a; }
  __syncthreads();
  for (int st = 256; st > 0; st >>= 1){ if (tid < st) red[tid] += red[tid+st]; __syncthreads(); }
  float Treg = red[0];
  __syncthreads();

  K_DECL(KA)

  for (int b = 0; b < 64; ++b){
    int i0 = b*64;
    // hoisted pure loads (arrays never written in this kernel; reorder across barriers is safe)
    unsigned long long xw_ = xbitsW[(size_t)b*512 + tid];
    float uu_ = U[(size_t)b*512 + tid];
    float4 cc = make_float4(0.f,0.f,0.f,0.f);
    float bc_ = 0.0f, bs0_ = 0.0f, bsc_ = 0.0f;
    if (g == 0){
      K_LOAD(KA, b);
      cc   = cst[i0 + t];
      bc_  = baseCorr[i0 + t];
      bs0_ = blkS0[b];
      bsc_ = blkS0C[b];
    }
    // phase 1: S_t partials, wave g covers labels 64g..64g+63 (verbatim round 2)
    unsigned long long w = colbitsP[(size_t)g*4096 + i0 + t];
    unsigned int lo = (unsigned)w, hi = (unsigned)(w >> 32);
    unsigned int nlo = ~lo, nhi = ~hi;
    float acc = 0.0f;
    #pragma unroll
    for (int j = 0; j < 32; ++j){
      unsigned int m = (nlo << (31-j)) & 0x80000000u;
      acc += __uint_as_float(__float_as_uint(p[g*64 + j]) ^ m);
    }
    #pragma unroll
    for (int j = 0; j < 32; ++j){
      unsigned int m = (nhi << (31-j)) & 0x80000000u;
      acc += __uint_as_float(__float_as_uint(p[g*64 + 32 + j]) ^ m);
    }
    part[g][t] = acc;
    __syncthreads();                              // B1

    if (g == 0){
      float S = 0.0f;
      #pragma unroll
      for (int gg = 0; gg < 8; ++gg) S += part[gg][t];
      float v = S - cc.x - rho*Preg - cc.y*Treg - bc_;
      // phase 2: 64 sequential steps, K in named registers, fully unrolled
      unsigned long long sg_ = 0ull;
      PH2(KA);
      if (t == 0){ sig = sg_; sbits[b] = sg_; }
      // P, T updates (wave0-only registers)
      float sv = ((sg_ >> t) & 1ull) ? cc.w : -cc.w;
      float sc = wave_allsum(sv);
      int pcs = __popcll(sg_);
      Preg += sc - bsc_;
      Treg += (float)(2*pcs - 64) - bs0_;
    }
    __syncthreads();                              // B2
    // phase 3: p update, one label per thread (verbatim round 2, loads hoisted)
    {
      unsigned long long sgv = sig;
      int pc = __popcll(xw_ ^ sgv);
      p[tid] = p[tid] + (float)(64 - 2*pc) - uu_;
    }
    __syncthreads();                              // B3
  }
}

// ---- exact integer scores + argmax one-hot
__global__ void k_scores(const unsigned long long* __restrict__ xbits,
                         const unsigned long long* __restrict__ sbits,
                         float* __restrict__ out){
  __shared__ unsigned long long sb[64];
  __shared__ int bestkey;
  int tid = threadIdx.x;  // 512
  if (tid < 64) sb[tid] = sbits[tid];
  if (tid == 0) bestkey = -1;
  __syncthreads();
  int acc = 0;
  #pragma unroll
  for (int w = 0; w < 64; ++w)
    acc += __popcll(xbits[(size_t)tid*64 + w] ^ sb[w]);
  int dot = 4096 - 2*acc;
  int ad  = dot < 0 ? -dot : dot;
  int key = (ad << 10) | (511 - tid);
  atomicMax(&bestkey, key);
  __syncthreads();
  int bl = 511 - (bestkey & 1023);
  float val = (float)(bestkey >> 10) * (1.0f/4096.0f);
  out[tid] = (tid == bl) ? val : 0.0f;
}

extern "C" void kernel_launch(void* const* d_in, const int* in_sizes, int n_in,
                              void* d_out, int out_size, void* d_ws, size_t ws_size,
                              hipStream_t stream){
  const float* s0  = (const float*)d_in[0];   // [4096]
  const float* llv = (const float*)d_in[1];   // [512][4096]
  float* out = (float*)d_out;                 // [512]
  char* ws = (char*)d_ws;

  unsigned long long* colbitsP = (unsigned long long*)(ws + OFF_COLB);
  unsigned long long* xbits    = (unsigned long long*)(ws + OFF_XBITS);
  unsigned long long* xbitsW   = (unsigned long long*)(ws + OFF_XBW);
  float*  Kf    = (float*)(ws + OFF_KF);
  float*  bcorr = (float*)(ws + OFF_BCORR);
  float*  U     = (float*)(ws + OFF_U);
  float4* cst   = (float4*)(ws + OFF_CST);
  float*  p0    = (float*)(ws + OFF_P0);
  unsigned long long* sbits = (unsigned long long*)(ws + OFF_SBITS);
  int*    colcnt = (int*)(ws + OFF_CNT);
  float*  hdr   = (float*)(ws + OFF_HDR);
  float*  bS0   = (float*)(ws + OFF_BS0);
  float*  bS0C  = (float*)(ws + OFF_BS0C);

  k_xbits<<<128, 256, 0, stream>>>(llv, xbits, xbitsW);
  k_bitT<<<dim3(8, 64), 64, 0, stream>>>(xbits, colbitsP);
  k_colc<<<16, 256, 0, stream>>>(colbitsP, colcnt);
  k_rho<<<1, 256, 0, stream>>>(colcnt, hdr);
  k_const<<<16, 256, 0, stream>>>(colcnt, hdr, s0, cst);
  k_kdiag<<<64, 256, 0, stream>>>(colbitsP, cst, s0, hdr, Kf, bcorr, bS0, bS0C);
  k_u<<<64, 512, 0, stream>>>(xbits, s0, U);
  k_pinit<<<512, 64, 0, stream>>>(llv, s0, p0);
  k_sweep2<<<1, 512, 0, stream>>>(colbitsP, xbitsW, Kf, bcorr, bS0, bS0C, U, cst, p0, s0, hdr, sbits);
  k_scores<<<1, 512, 0, stream>>>(xbits, sbits, out);
}